// Round 14
// baseline (184.972 us; speedup 1.0000x reference)
//
#include <hip/hip_runtime.h>
#include <hip/hip_bf16.h>
#include <math.h>

#define N_NODES 8192
#define N_EDGES 131072
#define NGRP 16
#define NLAY 2
#define NELM 4
#define SLOT_STRIDE 64     // fixed per-node slot region; P(deg>64) ~ 1e-15
#define N_SLOTS (N_NODES*SLOT_STRIDE)
constexpr float INV_AVG = 1.0f / 16.0f;
constexpr float PI_F = 3.14159265358979323846f;

// converted fp32 buffer layout (element offsets) -- only what k_gu/k_out need.
#define CV_EMB   0        // 256
#define CV_SC    256      // 32768 (natural [l][ty][c:64][d:64])
#define CV_PROD  33024    // 32
#define CV_RO0   33056    // 64
#define CV_RO1A  33120    // 1024
#define CV_RO1B  34144    // 16
#define CV_SC0T  34160    // 256 (layer-0 sc term per type: Wemb[ty] @ Wsc0[ty])
#define CVT_WORK 34160
#define CVT_N    34416

// swizzled bf16 MFMA B-fragment weight buffer: per layer 10240 shorts
#define SWZ_PER_L 10240
#define SWZ_N     20480

// k_setup fused-dispatch block ranges: [geom][cvt][swz][sc0tab]
#define B_GEOM 512
#define B_CVT  134
#define B_SWZ  80
#define SETUP_GRID (B_GEOM + B_CVT + B_SWZ + 1)

typedef __hip_bfloat16 bf16;
typedef __attribute__((ext_vector_type(8))) short bf16x8;
typedef __attribute__((ext_vector_type(4))) float f32x4;

__device__ __forceinline__ float silu_f(float x){ return x / (1.0f + __expf(-x)); }
__device__ __forceinline__ float bfbits2f(unsigned short u){
  return __uint_as_float(((unsigned)u) << 16);
}
__device__ __forceinline__ void unpack2(unsigned u, float& lo, float& hi){
  lo = __uint_as_float(u << 16);
  hi = __uint_as_float(u & 0xffff0000u);
}
__device__ __forceinline__ short f2bs(float v){
  union { bf16 b; short s; } u; u.b = __float2bfloat16(v); return u.s;
}
__device__ __forceinline__ float ldf(const void* p, int i, int flag){
  if (flag) return bfbits2f(((const unsigned short*)p)[i]);
  return ((const float*)p)[i];
}
// per-wave input dtype detection (reads first 128 ushorts of pos; L1/L2-hot).
__device__ __forceinline__ int detect_fl(const void* pos){
  int lane = threadIdx.x & 63;
  const unsigned short* u = (const unsigned short*)pos;
  float va = bfbits2f(u[2*lane]), vb = bfbits2f(u[2*lane+1]);
  bool bad = !(fabsf(va) <= 1000.0f) || !(fabsf(vb) <= 1000.0f);
  return (__ballot(bad) == 0ull) ? 1 : 0;
}
__device__ __forceinline__ void WSYNC(){ __builtin_amdgcn_wave_barrier(); }

// async global->LDS DMA: data never touches VGPRs.
__device__ __forceinline__ void gl_lds4(const void* g, void* l){
  __builtin_amdgcn_global_load_lds(
      (const __attribute__((address_space(1))) unsigned*)g,
      (__attribute__((address_space(3))) unsigned*)l, 4, 0, 0);
}

// ===== K1: fused {edge geom + fixed-stride CSR, cvt, weight-swz, sc0-table} ==
__global__ void k_setup(const void* __restrict__ pos, const int* __restrict__ types,
                        const int* __restrict__ ei,
                        const void* __restrict__ Wemb, const void* __restrict__ Wsc,
                        const void* __restrict__ wprod, const void* __restrict__ wro0,
                        const void* __restrict__ Wro1a, const void* __restrict__ wro1b,
                        const void* __restrict__ Wr1, const void* __restrict__ Wr2,
                        const void* __restrict__ Wr3,
                        int* __restrict__ cursor, int* __restrict__ sslot,
                        unsigned char* __restrict__ tsl, int* __restrict__ eslot,
                        unsigned short* __restrict__ Yb, float* __restrict__ rbuf,
                        float* __restrict__ cv, short* __restrict__ swz){
  int b = blockIdx.x, tix = threadIdx.x;
  int fl = detect_fl(pos);
  if (b < B_GEOM){                     // ---- edge geometry + slot assignment ----
    int e = b*256 + tix;
    int s = ei[e], d = ei[N_EDGES + e];
    int slot = (d << 6) + atomicAdd(&cursor[d], 1);
    sslot[slot] = s;
    tsl[slot] = (unsigned char)types[s];
    eslot[slot] = e;
    float vx = ldf(pos, d*3+0, fl) - ldf(pos, s*3+0, fl);
    float vy = ldf(pos, d*3+1, fl) - ldf(pos, s*3+1, fl);
    float vz = ldf(pos, d*3+2, fl) - ldf(pos, s*3+2, fl);
    float r = sqrtf(vx*vx + vy*vy + vz*vz + 1e-12f);
    float ir = 1.0f / r;
    float x = vx*ir, y = vy*ir, z = vz*ir;
    const float s3 = 1.7320508075688772f, s15 = 3.872983346207417f, s5 = 2.23606797749979f;
    const float s105 = 10.246950765959598f, s7 = 2.6457513110645907f;
    const float c35 = 2.091650066335189f, c21 = 1.6201851746019651f;
    float x2 = x*x, y2 = y*y, z2 = z*z;
    float ys[16] = {
      1.0f, s3*x, s3*y, s3*z,
      s15*x*y, s15*y*z, 0.5f*s5*(3.0f*z2-1.0f), s15*x*z,
      0.5f*s15*(x2-y2), c35*y*(3.0f*x2-y2), s105*x*y*z, c21*y*(5.0f*z2-1.0f),
      0.5f*s7*(5.0f*z2*z-3.0f*z), c21*x*(5.0f*z2-1.0f), 0.5f*s105*z*(x2-y2),
      c35*x*(x2-3.0f*y2) };
    union { bf16 bb[16]; uint4 u[2]; } pk;
#pragma unroll
    for (int k = 0; k < 16; k++) pk.bb[k] = __float2bfloat16(ys[k]);
    uint4* yp = (uint4*)(Yb + (size_t)e*16);   // LINEAR by edge (coalesced)
    yp[0] = pk.u[0];
    yp[1] = pk.u[1];
    rbuf[slot] = r;
    return;
  }
  if (b < B_GEOM + B_CVT){             // ---- fp32 conversion ----
    int i = (b - B_GEOM)*256 + tix;
    if (i < 256)  { cv[CV_EMB + i] = ldf(Wemb, i, fl); return; }
    if (i < 33024){ int j=i-256;   cv[CV_SC  + j] = ldf(Wsc,  j, fl); return; }
    if (i < 33056){ int j=i-33024; cv[CV_PROD+ j] = ldf(wprod,j, fl); return; }
    if (i < 33120){ int j=i-33056; cv[CV_RO0 + j] = ldf(wro0, j, fl); return; }
    if (i < 34144){ int j=i-33120; cv[CV_RO1A+ j] = ldf(Wro1a,j, fl); return; }
    if (i < CVT_WORK){ int j=i-34144; cv[CV_RO1B+ j] = ldf(wro1b,j, fl); return; }
    return;
  }
  if (b < B_GEOM + B_CVT + B_SWZ){     // ---- MFMA B-fragment bf16 weights ----
    int i = (b - B_GEOM - B_CVT)*256 + tix;   // 20480 exact
    int l = i / SWZ_PER_L, w = i % SWZ_PER_L;
    float v;
    if (w < 2048){
      int t = w >> 9, q = (w >> 7) & 3, n = (w >> 3) & 15, j = w & 7;
      int k = q*8 + j;
      v = (k < 8) ? ldf(Wr1, l*512 + k*64 + t*16 + n, fl) : 0.0f;
    } else if (w < 6144){
      int w2 = w - 2048;
      int nt = w2 >> 10, kt = (w2 >> 9) & 1, q = (w2 >> 7) & 3, n = (w2 >> 3) & 15, j = w2 & 7;
      int k = kt*32 + q*8 + j;
      v = ldf(Wr2, l*4096 + k*64 + nt*16 + n, fl);
    } else {
      int w3 = w - 6144;
      int nt = w3 >> 10, kt = (w3 >> 9) & 1, q = (w3 >> 7) & 3, n = (w3 >> 3) & 15, j = w3 & 7;
      int k = kt*32 + q*8 + j;
      v = ldf(Wr3, l*4096 + k*64 + nt*16 + n, fl);
    }
    swz[i] = f2bs(v);
    return;
  }
  // ---- layer-0 sc table: sc0t[ty][d] = sum_c Wemb[ty][c] * Wsc0[ty][c][d] ----
  {
    int ty = tix >> 6, d = tix & 63;
    float s = 0.0f;
#pragma unroll 8
    for (int c = 0; c < 64; c++)
      s += ldf(Wemb, ty*64 + c, fl) * ldf(Wsc, ty*4096 + c*64 + d, fl);
    cv[CV_SC0T + tix] = s;
  }
}

// ====== fused node kernel: 256-thread WG = FOUR independent node-waves ======
// R13 wave body byte-identical; all state indexed by wv; ZERO block barriers.
// Tests the WG-grain limiter: 2048 WGs x 4 waves vs 8192 x 1.
#define ROWS 72
template<int LAYER_KIND>
__global__ void __launch_bounds__(256) k_gu(const short* __restrict__ sw,
        const float* __restrict__ rbuf, const unsigned char* __restrict__ tsl,
        const int* __restrict__ sslot, const int* __restrict__ eslot,
        const float* __restrict__ h_old,
        float* __restrict__ h_new, const unsigned short* __restrict__ Yb,
        const int* __restrict__ cursor, const int* __restrict__ types,
        const float* __restrict__ Wsc, const float* __restrict__ wprod,
        const float* __restrict__ wemb, const float* __restrict__ sc0t,
        const float* __restrict__ wro0,
        const float* __restrict__ Wro1a, const float* __restrict__ wro1b,
        const int* __restrict__ batch, float* __restrict__ ene2){
  __shared__ __align__(16) short A_[4][16*ROWS];                     // 9 KB
  __shared__ __align__(16) float hS[LAYER_KIND ? 64 : 1][64];        // 16 KB (L1)
  __shared__ __align__(16) unsigned short yS[4][16][16];             // 2 KB
  __shared__ float hn_l[4][64];
  int tix = threadIdx.x;
  int wv = tix >> 6, lane = tix & 63;
  int q = lane >> 4, nn = lane & 15;
  int n = blockIdx.x * 4 + wv;
  int beg = n << 6;
  short* A = A_[wv];
  float (*hSw)[64] = &hS[LAYER_KIND ? wv*16 : 0];

  const bf16x8* S1 = (const bf16x8*)(sw);
  const bf16x8* S2 = (const bf16x8*)(sw + 2048);
  const bf16x8* S3 = (const bf16x8*)(sw + 6144);

  // layer-0 embedding rows (4 types x 64 ch) in registers
  float e0=0.f, e1=0.f, e2=0.f, e3=0.f;
  if (LAYER_KIND == 0){
    e0 = wemb[lane]; e1 = wemb[64+lane]; e2 = wemb[128+lane]; e3 = wemb[192+lane];
  }

  // ---- prefetch chunk-0 metadata in parallel with the cursor load ----
  int dcnt = cursor[n];
  int ev  = eslot[beg + nn];
  int sv  = (LAYER_KIND == 1) ? sslot[beg + nn] : 0;
  int tvp = (LAYER_KIND == 0) ? (int)tsl[beg + nn] : 0;
  float rv = rbuf[beg + nn];
  int end = beg + dcnt;

  float acc[16];
#pragma unroll
  for (int s = 0; s < 16; s++) acc[s] = 0.0f;

  int cb = beg;
  do {
    WSYNC();   // fence: prior chunk's LDS reads precede this chunk's DMA/MLP
    // ---------- phase A: issue DMAs ----------
    // Y rows via eslot indirection: 2 DMAs x 8 rows x 32B; per-lane global src
    {
      int er0 = __shfl(ev, (lane >> 3)) & (N_EDGES - 1);
      gl_lds4((const char*)Yb + (size_t)er0*32 + (lane & 7)*4, &yS[wv][0][0]);
      int er1 = __shfl(ev, 8 + (lane >> 3)) & (N_EDGES - 1);
      gl_lds4((const char*)Yb + (size_t)er1*32 + (lane & 7)*4, &yS[wv][8][0]);
    }
    int tv = tvp;
    if (LAYER_KIND == 1){
#pragma unroll
      for (int i = 0; i < 16; i++){   // fixed 16: no cursor dependence
        int src = __builtin_amdgcn_readlane(sv, i) & (N_NODES - 1);
        gl_lds4(h_old + (size_t)src*64 + lane, &hSw[i][0]);
      }
    }
    // prefetch next chunk's metadata (issued early, consumed next iteration)
    int nx = min(cb + 16 + nn, N_SLOTS - 1);
    int ev_n = eslot[nx];
    int sv_n = (LAYER_KIND == 1) ? sslot[nx] : 0;
    int tv_n = (LAYER_KIND == 0) ? (int)tsl[nx] : 0;
    float rv_n = rbuf[nx];
    // ---------- phase B: wave-private MFMA radial MLP (hides DMA) ----------
    {
      float r = rv;
      float xc = r * 0.2f;
      float f = 0.0f;
      if (xc < 1.0f){
        float x3 = xc*xc*xc, x6 = x3*x3, x7 = x6*xc, x8 = x7*xc;
        f = 1.0f - 28.0f*x6 + 48.0f*x7 - 21.0f*x8;
      }
      float bs = 0.6324555320336759f * f / r;
      float t0 = PI_F * r * 0.2f;
      bf16x8 af1 = {0,0,0,0,0,0,0,0};
      if (q == 0){
#pragma unroll
        for (int j = 0; j < 8; j++) af1[j] = f2bs(bs * __sinf((float)(j+1) * t0));
      }
      f32x4 macc[4];
#pragma unroll
      for (int t = 0; t < 4; t++){
        bf16x8 b = S1[t*64 + q*16 + nn];
        f32x4 z = {0.f,0.f,0.f,0.f};
        macc[t] = __builtin_amdgcn_mfma_f32_16x16x32_bf16(af1, b, z, 0, 0, 0);
      }
#pragma unroll
      for (int t = 0; t < 4; t++)
#pragma unroll
        for (int rg = 0; rg < 4; rg++)
          A[(q*4+rg)*ROWS + t*16 + nn] = f2bs(silu_f(macc[t][rg]));
      WSYNC();
      bf16x8 a0 = *(const bf16x8*)&A[nn*ROWS + 0*32 + q*8];
      bf16x8 a1 = *(const bf16x8*)&A[nn*ROWS + 1*32 + q*8];
      WSYNC();
#pragma unroll
      for (int t = 0; t < 4; t++){
        f32x4 z = {0.f,0.f,0.f,0.f};
        bf16x8 b0 = S2[t*128 + 0*64 + q*16 + nn];
        bf16x8 b1 = S2[t*128 + 1*64 + q*16 + nn];
        z = __builtin_amdgcn_mfma_f32_16x16x32_bf16(a0, b0, z, 0, 0, 0);
        z = __builtin_amdgcn_mfma_f32_16x16x32_bf16(a1, b1, z, 0, 0, 0);
        macc[t] = z;
      }
#pragma unroll
      for (int t = 0; t < 4; t++)
#pragma unroll
        for (int rg = 0; rg < 4; rg++)
          A[(q*4+rg)*ROWS + t*16 + nn] = f2bs(silu_f(macc[t][rg]));
      WSYNC();
      a0 = *(const bf16x8*)&A[nn*ROWS + 0*32 + q*8];
      a1 = *(const bf16x8*)&A[nn*ROWS + 1*32 + q*8];
      WSYNC();
#pragma unroll
      for (int t = 0; t < 4; t++){
        f32x4 z = {0.f,0.f,0.f,0.f};
        bf16x8 b0 = S3[t*128 + 0*64 + q*16 + nn];
        bf16x8 b1 = S3[t*128 + 1*64 + q*16 + nn];
        z = __builtin_amdgcn_mfma_f32_16x16x32_bf16(a0, b0, z, 0, 0, 0);
        z = __builtin_amdgcn_mfma_f32_16x16x32_bf16(a1, b1, z, 0, 0, 0);
        macc[t] = z;
      }
      // final Rw stays in A: layout A[slot*ROWS + ch]
#pragma unroll
      for (int t = 0; t < 4; t++)
#pragma unroll
        for (int rg = 0; rg < 4; rg++)
          A[(q*4+rg)*ROWS + t*16 + nn] = f2bs(macc[t][rg]);
      WSYNC();
    }
    // ---------- phase C: wait DMAs, accumulate (all wave-private) ----------
    asm volatile("s_waitcnt vmcnt(0)" ::: "memory");
    __builtin_amdgcn_sched_barrier(0);
    int cnt = min(16, end - cb);
    for (int i = 0; i < cnt; i++){
      float rw = bfbits2f((unsigned short)A[i*ROWS + lane]);  // 2-way alias
      float hv;
      if (LAYER_KIND == 0){
        int ty = __builtin_amdgcn_readlane(tv, i);
        hv = (ty & 2) ? ((ty & 1) ? e3 : e2) : ((ty & 1) ? e1 : e0);
      } else {
        hv = hSw[i][lane];
      }
      float g = rw * hv;
      const uint4* yq = (const uint4*)&yS[wv][i][0];   // uniform -> broadcast
      uint4 ya = yq[0], yb = yq[1];
      float lo, hi;
      unpack2(ya.x, lo, hi); acc[0]  += g*lo; acc[1]  += g*hi;
      unpack2(ya.y, lo, hi); acc[2]  += g*lo; acc[3]  += g*hi;
      unpack2(ya.z, lo, hi); acc[4]  += g*lo; acc[5]  += g*hi;
      unpack2(ya.w, lo, hi); acc[6]  += g*lo; acc[7]  += g*hi;
      unpack2(yb.x, lo, hi); acc[8]  += g*lo; acc[9]  += g*hi;
      unpack2(yb.y, lo, hi); acc[10] += g*lo; acc[11] += g*hi;
      unpack2(yb.z, lo, hi); acc[12] += g*lo; acc[13] += g*hi;
      unpack2(yb.w, lo, hi); acc[14] += g*lo; acc[15] += g*hi;
    }
    ev = ev_n; sv = sv_n; tvp = tv_n; rv = rv_n;
    cb += 16;
  } while (cb < end);
#pragma unroll
  for (int s = 0; s < 16; s++) acc[s] *= INV_AVG;

  int ty = __builtin_amdgcn_readfirstlane(types[n]);
  float sc;
  if (LAYER_KIND == 0){
    sc = sc0t[ty*64 + lane];                   // precomputed per-type table
  } else {
    const float* Ws = Wsc + (size_t)ty*4096;
    const float* hrow = h_old + (size_t)n*64;
    float sc0 = 0.f, sc1 = 0.f, sc2 = 0.f, sc3 = 0.f;
#pragma unroll
    for (int c = 0; c < 64; c += 4){
      sc0 += hrow[c+0] * Ws[(c+0)*64 + lane];
      sc1 += hrow[c+1] * Ws[(c+1)*64 + lane];
      sc2 += hrow[c+2] * Ws[(c+2)*64 + lane];
      sc3 += hrow[c+3] * Ws[(c+3)*64 + lane];
    }
    sc = (sc0 + sc1) + (sc2 + sc3);
  }

  float inv0 = acc[0];
  float inv1 = acc[1]*acc[1] + acc[2]*acc[2] + acc[3]*acc[3];
  float inv2 = acc[4]*acc[4] + acc[5]*acc[5] + acc[6]*acc[6] + acc[7]*acc[7]
             + acc[8]*acc[8];
  float inv3 = acc[9]*acc[9] + acc[10]*acc[10] + acc[11]*acc[11] + acc[12]*acc[12]
             + acc[13]*acc[13] + acc[14]*acc[14] + acc[15]*acc[15];
  const float* wp = wprod + ty*4;
  float hn = inv0*wp[0] + inv1*wp[1] + inv2*wp[2] + inv3*wp[3] + sc;
  if (LAYER_KIND == 0)
    h_new[(size_t)n*64 + lane] = hn;   // layer-1 output consumed in-kernel

  float ev_;
  if (LAYER_KIND == 0){
    float p = hn * wro0[lane];
#pragma unroll
    for (int off = 32; off >= 1; off >>= 1) p += __shfl_xor(p, off, 64);
    ev_ = p;
  } else {
    hn_l[wv][lane] = hn;
    WSYNC();
    int j = lane & 15;
    float pj = 0.0f;
#pragma unroll
    for (int c = 0; c < 64; c++)
      pj += hn_l[wv][c] * Wro1a[c*16 + j];
    float evj = silu_f(pj) * wro1b[j];
    evj += __shfl_xor(evj, 8, 64);
    evj += __shfl_xor(evj, 4, 64);
    evj += __shfl_xor(evj, 2, 64);
    evj += __shfl_xor(evj, 1, 64);
    ev_ = evj;
  }
  // contention-spread energy: consecutive nodes hit different copies
  if (lane == 0) atomicAdd(&ene2[(n & 7)*NGRP + batch[n]], ev_);
}

// ---------------- final output: reduce ene2 copies + format convert ----------
__global__ void k_out(const float* __restrict__ ene2, const void* __restrict__ pos,
                      void* __restrict__ out){
  int fl = detect_fl(pos);
  int t = threadIdx.x;
  if (t < NGRP){
    float v = 0.0f;
#pragma unroll
    for (int k = 0; k < 8; k++) v += ene2[k*NGRP + t];
    if (fl) ((bf16*)out)[t] = __float2bfloat16(v);
    else    ((float*)out)[t] = v;
  }
}

static inline size_t rup(size_t x){ return (x + 255) & ~(size_t)255; }

extern "C" void kernel_launch(void* const* d_in, const int* in_sizes, int n_in,
                              void* d_out, int out_size, void* d_ws, size_t ws_size,
                              hipStream_t stream) {
  const void* pos   = d_in[0];
  const int*  types = (const int*)d_in[1];
  const int*  ei    = (const int*)d_in[2];
  const int*  batch = (const int*)d_in[3];
  const void* Wemb  = d_in[4];
  const void* Wr1   = d_in[5];
  const void* Wr2   = d_in[6];
  const void* Wr3   = d_in[7];
  const void* Wsc   = d_in[8];
  const void* wprod = d_in[9];
  const void* wro0  = d_in[10];
  const void* Wro1a = d_in[11];
  const void* wro1b = d_in[12];

  char* w = (char*)d_ws;
  float* ene2     = (float*)w; w += 512;                      // 8 copies x 16
  int*   cursor   = (int*)  w; w += rup((size_t)N_NODES*4);   // contiguous w/ ene2
  float* cv       = (float*)w; w += rup((size_t)CVT_N*4);
  short* swz      = (short*)w; w += rup((size_t)SWZ_N*2);
  int*   sslot    = (int*)  w; w += rup((size_t)N_SLOTS*4) + 256;
  unsigned char* tsl = (unsigned char*)w; w += rup((size_t)N_SLOTS) + 256;
  int*   eslot    = (int*)  w; w += rup((size_t)N_SLOTS*4) + 256;
  float* hbuf     = (float*)w; w += rup((size_t)N_NODES*64*4);
  float* rbuf     = (float*)w; w += rup((size_t)N_SLOTS*4) + 256;
  unsigned short* Yb = (unsigned short*)w; w += rup((size_t)N_EDGES*16*2);
  w += 4096;   // slack

  // one memset zeroes ene2 (512B) + cursor (32KB) in one shot
  hipMemsetAsync(ene2, 0, 512 + (size_t)N_NODES*4, stream);

  k_setup<<<SETUP_GRID, 256, 0, stream>>>(pos, types, ei,
      Wemb, Wsc, wprod, wro0, Wro1a, wro1b, Wr1, Wr2, Wr3,
      cursor, sslot, tsl, eslot, Yb, rbuf, cv, swz);

  k_gu<0><<<N_NODES/4, 256, 0, stream>>>(swz, rbuf, tsl, sslot, eslot,
      hbuf /*unused*/, hbuf /*h_new*/, Yb, cursor, types,
      cv + CV_SC, cv + CV_PROD, cv + CV_EMB, cv + CV_SC0T,
      cv + CV_RO0, cv + CV_RO1A, cv + CV_RO1B, batch, ene2);
  k_gu<1><<<N_NODES/4, 256, 0, stream>>>(swz + SWZ_PER_L, rbuf, tsl, sslot, eslot,
      hbuf /*h_old*/, hbuf /*unused*/, Yb, cursor, types,
      cv + CV_SC + (size_t)NELM*4096, cv + CV_PROD + NELM*4, cv + CV_EMB,
      cv + CV_SC0T, cv + CV_RO0, cv + CV_RO1A, cv + CV_RO1B, batch, ene2);

  k_out<<<1, 64, 0, stream>>>(ene2, pos, d_out);
}

// Round 15
// 172.609 us; speedup vs baseline: 1.0716x; 1.0716x over previous
//
#include <hip/hip_runtime.h>
#include <hip/hip_bf16.h>
#include <math.h>

#define N_NODES 8192
#define N_EDGES 131072
#define NGRP 16
#define NLAY 2
#define NELM 4
#define SLOT_STRIDE 64     // fixed per-node slot region; P(deg>64) ~ 1e-15
#define N_SLOTS (N_NODES*SLOT_STRIDE)
constexpr float INV_AVG = 1.0f / 16.0f;
constexpr float PI_F = 3.14159265358979323846f;

// converted fp32 buffer layout (element offsets) -- only what k_gu/k_out need.
#define CV_EMB   0        // 256
#define CV_SC    256      // 32768 (natural [l][ty][c:64][d:64])
#define CV_PROD  33024    // 32
#define CV_RO0   33056    // 64
#define CV_RO1A  33120    // 1024
#define CV_RO1B  34144    // 16
#define CV_SC0T  34160    // 256 (layer-0 sc term per type: Wemb[ty] @ Wsc0[ty])
#define CVT_WORK 34160
#define CVT_N    34416

// swizzled bf16 MFMA B-fragment weight buffer: per layer 10240 shorts
#define SWZ_PER_L 10240
#define SWZ_N     20480

// k_setup fused-dispatch block ranges: [geom][cvt][swz][sc0tab]
#define B_GEOM 512
#define B_CVT  134
#define B_SWZ  80
#define SETUP_GRID (B_GEOM + B_CVT + B_SWZ + 1)

typedef __hip_bfloat16 bf16;
typedef __attribute__((ext_vector_type(8))) short bf16x8;
typedef __attribute__((ext_vector_type(4))) float f32x4;

__device__ __forceinline__ float silu_f(float x){ return x / (1.0f + __expf(-x)); }
__device__ __forceinline__ float bfbits2f(unsigned short u){
  return __uint_as_float(((unsigned)u) << 16);
}
__device__ __forceinline__ void unpack2(unsigned u, float& lo, float& hi){
  lo = __uint_as_float(u << 16);
  hi = __uint_as_float(u & 0xffff0000u);
}
__device__ __forceinline__ short f2bs(float v){
  union { bf16 b; short s; } u; u.b = __float2bfloat16(v); return u.s;
}
__device__ __forceinline__ float ldf(const void* p, int i, int flag){
  if (flag) return bfbits2f(((const unsigned short*)p)[i]);
  return ((const float*)p)[i];
}
// per-wave input dtype detection (reads first 128 ushorts of pos; L1/L2-hot).
__device__ __forceinline__ int detect_fl(const void* pos){
  int lane = threadIdx.x & 63;
  const unsigned short* u = (const unsigned short*)pos;
  float va = bfbits2f(u[2*lane]), vb = bfbits2f(u[2*lane+1]);
  bool bad = !(fabsf(va) <= 1000.0f) || !(fabsf(vb) <= 1000.0f);
  return (__ballot(bad) == 0ull) ? 1 : 0;
}
__device__ __forceinline__ void WSYNC(){ __builtin_amdgcn_wave_barrier(); }

// async global->LDS DMA: data never touches VGPRs.
__device__ __forceinline__ void gl_lds4(const void* g, void* l){
  __builtin_amdgcn_global_load_lds(
      (const __attribute__((address_space(1))) unsigned*)g,
      (__attribute__((address_space(3))) unsigned*)l, 4, 0, 0);
}

// ===== K1: fused {edge geom + fixed-stride CSR, cvt, weight-swz, sc0-table} ==
// Geom writes Y LINEARLY by edge (coalesced); scatters only
// {sslot,tsl,eslot,rbuf} = 13B/edge.
__global__ void k_setup(const void* __restrict__ pos, const int* __restrict__ types,
                        const int* __restrict__ ei,
                        const void* __restrict__ Wemb, const void* __restrict__ Wsc,
                        const void* __restrict__ wprod, const void* __restrict__ wro0,
                        const void* __restrict__ Wro1a, const void* __restrict__ wro1b,
                        const void* __restrict__ Wr1, const void* __restrict__ Wr2,
                        const void* __restrict__ Wr3,
                        int* __restrict__ cursor, int* __restrict__ sslot,
                        unsigned char* __restrict__ tsl, int* __restrict__ eslot,
                        unsigned short* __restrict__ Yb, float* __restrict__ rbuf,
                        float* __restrict__ cv, short* __restrict__ swz){
  int b = blockIdx.x, tix = threadIdx.x;
  int fl = detect_fl(pos);
  if (b < B_GEOM){                     // ---- edge geometry + slot assignment ----
    int e = b*256 + tix;
    int s = ei[e], d = ei[N_EDGES + e];
    int slot = (d << 6) + atomicAdd(&cursor[d], 1);
    sslot[slot] = s;
    tsl[slot] = (unsigned char)types[s];
    eslot[slot] = e;
    float vx = ldf(pos, d*3+0, fl) - ldf(pos, s*3+0, fl);
    float vy = ldf(pos, d*3+1, fl) - ldf(pos, s*3+1, fl);
    float vz = ldf(pos, d*3+2, fl) - ldf(pos, s*3+2, fl);
    float r = sqrtf(vx*vx + vy*vy + vz*vz + 1e-12f);
    float ir = 1.0f / r;
    float x = vx*ir, y = vy*ir, z = vz*ir;
    const float s3 = 1.7320508075688772f, s15 = 3.872983346207417f, s5 = 2.23606797749979f;
    const float s105 = 10.246950765959598f, s7 = 2.6457513110645907f;
    const float c35 = 2.091650066335189f, c21 = 1.6201851746019651f;
    float x2 = x*x, y2 = y*y, z2 = z*z;
    float ys[16] = {
      1.0f, s3*x, s3*y, s3*z,
      s15*x*y, s15*y*z, 0.5f*s5*(3.0f*z2-1.0f), s15*x*z,
      0.5f*s15*(x2-y2), c35*y*(3.0f*x2-y2), s105*x*y*z, c21*y*(5.0f*z2-1.0f),
      0.5f*s7*(5.0f*z2*z-3.0f*z), c21*x*(5.0f*z2-1.0f), 0.5f*s105*z*(x2-y2),
      c35*x*(x2-3.0f*y2) };
    union { bf16 bb[16]; uint4 u[2]; } pk;
#pragma unroll
    for (int k = 0; k < 16; k++) pk.bb[k] = __float2bfloat16(ys[k]);
    uint4* yp = (uint4*)(Yb + (size_t)e*16);   // LINEAR by edge (coalesced)
    yp[0] = pk.u[0];
    yp[1] = pk.u[1];
    rbuf[slot] = r;
    return;
  }
  if (b < B_GEOM + B_CVT){             // ---- fp32 conversion ----
    int i = (b - B_GEOM)*256 + tix;
    if (i < 256)  { cv[CV_EMB + i] = ldf(Wemb, i, fl); return; }
    if (i < 33024){ int j=i-256;   cv[CV_SC  + j] = ldf(Wsc,  j, fl); return; }
    if (i < 33056){ int j=i-33024; cv[CV_PROD+ j] = ldf(wprod,j, fl); return; }
    if (i < 33120){ int j=i-33056; cv[CV_RO0 + j] = ldf(wro0, j, fl); return; }
    if (i < 34144){ int j=i-33120; cv[CV_RO1A+ j] = ldf(Wro1a,j, fl); return; }
    if (i < CVT_WORK){ int j=i-34144; cv[CV_RO1B+ j] = ldf(wro1b,j, fl); return; }
    return;
  }
  if (b < B_GEOM + B_CVT + B_SWZ){     // ---- MFMA B-fragment bf16 weights ----
    int i = (b - B_GEOM - B_CVT)*256 + tix;   // 20480 exact
    int l = i / SWZ_PER_L, w = i % SWZ_PER_L;
    float v;
    if (w < 2048){
      int t = w >> 9, q = (w >> 7) & 3, n = (w >> 3) & 15, j = w & 7;
      int k = q*8 + j;
      v = (k < 8) ? ldf(Wr1, l*512 + k*64 + t*16 + n, fl) : 0.0f;
    } else if (w < 6144){
      int w2 = w - 2048;
      int nt = w2 >> 10, kt = (w2 >> 9) & 1, q = (w2 >> 7) & 3, n = (w2 >> 3) & 15, j = w2 & 7;
      int k = kt*32 + q*8 + j;
      v = ldf(Wr2, l*4096 + k*64 + nt*16 + n, fl);
    } else {
      int w3 = w - 6144;
      int nt = w3 >> 10, kt = (w3 >> 9) & 1, q = (w3 >> 7) & 3, n = (w3 >> 3) & 15, j = w3 & 7;
      int k = kt*32 + q*8 + j;
      v = ldf(Wr3, l*4096 + k*64 + nt*16 + n, fl);
    }
    swz[i] = f2bs(v);
    return;
  }
  // ---- layer-0 sc table: sc0t[ty][d] = sum_c Wemb[ty][c] * Wsc0[ty][c][d] ----
  {
    int ty = tix >> 6, d = tix & 63;
    float s = 0.0f;
#pragma unroll 8
    for (int c = 0; c < 64; c++)
      s += ldf(Wemb, ty*64 + c, fl) * ldf(Wsc, ty*4096 + c*64 + d, fl);
    cv[CV_SC0T + tix] = s;
  }
}

// ====== fused node kernel, ONE WAVE PER BLOCK (node = blockIdx.x) ======
// R13-verified body; single change vs R13: h-gather bounded by cnt (computed
// at loop top from registers -- no new dependence) instead of fixed 16,
// eliminating ~8 wasted 256B DMAs per node on tail chunks.
#define ROWS 72
template<int LAYER_KIND>
__global__ void __launch_bounds__(64) k_gu(const short* __restrict__ sw,
        const float* __restrict__ rbuf, const unsigned char* __restrict__ tsl,
        const int* __restrict__ sslot, const int* __restrict__ eslot,
        const float* __restrict__ h_old,
        float* __restrict__ h_new, const unsigned short* __restrict__ Yb,
        const int* __restrict__ cursor, const int* __restrict__ types,
        const float* __restrict__ Wsc, const float* __restrict__ wprod,
        const float* __restrict__ wemb, const float* __restrict__ sc0t,
        const float* __restrict__ wro0,
        const float* __restrict__ Wro1a, const float* __restrict__ wro1b,
        const int* __restrict__ batch, float* __restrict__ ene2){
  __shared__ __align__(16) short A_[16*ROWS];                    // 2.25 KB
  __shared__ __align__(16) float hS[LAYER_KIND ? 16 : 1][64];    // 4 KB (L1)
  __shared__ __align__(16) unsigned short yS[16][16];            // 0.5 KB
  __shared__ float hn_l[64];
  int lane = threadIdx.x;
  int q = lane >> 4, nn = lane & 15;
  int n = blockIdx.x;
  int beg = n << 6;
  short* A = A_;

  const bf16x8* S1 = (const bf16x8*)(sw);
  const bf16x8* S2 = (const bf16x8*)(sw + 2048);
  const bf16x8* S3 = (const bf16x8*)(sw + 6144);

  // layer-0 embedding rows (4 types x 64 ch) in registers
  float e0=0.f, e1=0.f, e2=0.f, e3=0.f;
  if (LAYER_KIND == 0){
    e0 = wemb[lane]; e1 = wemb[64+lane]; e2 = wemb[128+lane]; e3 = wemb[192+lane];
  }

  // ---- prefetch chunk-0 metadata in parallel with the cursor load ----
  int dcnt = cursor[n];
  int ev  = eslot[beg + nn];
  int sv  = (LAYER_KIND == 1) ? sslot[beg + nn] : 0;
  int tvp = (LAYER_KIND == 0) ? (int)tsl[beg + nn] : 0;
  float rv = rbuf[beg + nn];
  int end = beg + dcnt;

  float acc[16];
#pragma unroll
  for (int s = 0; s < 16; s++) acc[s] = 0.0f;

  int cb = beg;
  do {
    int cnt = min(16, end - cb);     // known from registers; no memory dep
    WSYNC();   // fence: prior chunk's LDS reads precede this chunk's DMA/MLP
    // ---------- phase A: issue DMAs ----------
    // Y rows via eslot indirection: 2 DMAs x 8 rows x 32B; per-lane global src
    {
      int er0 = __shfl(ev, (lane >> 3)) & (N_EDGES - 1);
      gl_lds4((const char*)Yb + (size_t)er0*32 + (lane & 7)*4, &yS[0][0]);
      int er1 = __shfl(ev, 8 + (lane >> 3)) & (N_EDGES - 1);
      gl_lds4((const char*)Yb + (size_t)er1*32 + (lane & 7)*4, &yS[8][0]);
    }
    int tv = tvp;
    if (LAYER_KIND == 1){
      for (int i = 0; i < cnt; i++){   // bounded: no wasted tail DMAs
        int src = __builtin_amdgcn_readlane(sv, i) & (N_NODES - 1);
        gl_lds4(h_old + (size_t)src*64 + lane, &hS[i][0]);
      }
    }
    // prefetch next chunk's metadata (issued early, consumed next iteration)
    int nx = min(cb + 16 + nn, N_SLOTS - 1);
    int ev_n = eslot[nx];
    int sv_n = (LAYER_KIND == 1) ? sslot[nx] : 0;
    int tv_n = (LAYER_KIND == 0) ? (int)tsl[nx] : 0;
    float rv_n = rbuf[nx];
    // ---------- phase B: wave-private MFMA radial MLP (hides DMA) ----------
    {
      float r = rv;
      float xc = r * 0.2f;
      float f = 0.0f;
      if (xc < 1.0f){
        float x3 = xc*xc*xc, x6 = x3*x3, x7 = x6*xc, x8 = x7*xc;
        f = 1.0f - 28.0f*x6 + 48.0f*x7 - 21.0f*x8;
      }
      float bs = 0.6324555320336759f * f / r;
      float t0 = PI_F * r * 0.2f;
      bf16x8 af1 = {0,0,0,0,0,0,0,0};
      if (q == 0){
#pragma unroll
        for (int j = 0; j < 8; j++) af1[j] = f2bs(bs * __sinf((float)(j+1) * t0));
      }
      f32x4 macc[4];
#pragma unroll
      for (int t = 0; t < 4; t++){
        bf16x8 b = S1[t*64 + q*16 + nn];
        f32x4 z = {0.f,0.f,0.f,0.f};
        macc[t] = __builtin_amdgcn_mfma_f32_16x16x32_bf16(af1, b, z, 0, 0, 0);
      }
#pragma unroll
      for (int t = 0; t < 4; t++)
#pragma unroll
        for (int rg = 0; rg < 4; rg++)
          A[(q*4+rg)*ROWS + t*16 + nn] = f2bs(silu_f(macc[t][rg]));
      WSYNC();
      bf16x8 a0 = *(const bf16x8*)&A[nn*ROWS + 0*32 + q*8];
      bf16x8 a1 = *(const bf16x8*)&A[nn*ROWS + 1*32 + q*8];
      WSYNC();
#pragma unroll
      for (int t = 0; t < 4; t++){
        f32x4 z = {0.f,0.f,0.f,0.f};
        bf16x8 b0 = S2[t*128 + 0*64 + q*16 + nn];
        bf16x8 b1 = S2[t*128 + 1*64 + q*16 + nn];
        z = __builtin_amdgcn_mfma_f32_16x16x32_bf16(a0, b0, z, 0, 0, 0);
        z = __builtin_amdgcn_mfma_f32_16x16x32_bf16(a1, b1, z, 0, 0, 0);
        macc[t] = z;
      }
#pragma unroll
      for (int t = 0; t < 4; t++)
#pragma unroll
        for (int rg = 0; rg < 4; rg++)
          A[(q*4+rg)*ROWS + t*16 + nn] = f2bs(silu_f(macc[t][rg]));
      WSYNC();
      a0 = *(const bf16x8*)&A[nn*ROWS + 0*32 + q*8];
      a1 = *(const bf16x8*)&A[nn*ROWS + 1*32 + q*8];
      WSYNC();
#pragma unroll
      for (int t = 0; t < 4; t++){
        f32x4 z = {0.f,0.f,0.f,0.f};
        bf16x8 b0 = S3[t*128 + 0*64 + q*16 + nn];
        bf16x8 b1 = S3[t*128 + 1*64 + q*16 + nn];
        z = __builtin_amdgcn_mfma_f32_16x16x32_bf16(a0, b0, z, 0, 0, 0);
        z = __builtin_amdgcn_mfma_f32_16x16x32_bf16(a1, b1, z, 0, 0, 0);
        macc[t] = z;
      }
      // final Rw stays in A: layout A[slot*ROWS + ch]
#pragma unroll
      for (int t = 0; t < 4; t++)
#pragma unroll
        for (int rg = 0; rg < 4; rg++)
          A[(q*4+rg)*ROWS + t*16 + nn] = f2bs(macc[t][rg]);
      WSYNC();
    }
    // ---------- phase C: wait DMAs, accumulate (all wave-private) ----------
    asm volatile("s_waitcnt vmcnt(0)" ::: "memory");
    __builtin_amdgcn_sched_barrier(0);
    for (int i = 0; i < cnt; i++){
      float rw = bfbits2f((unsigned short)A[i*ROWS + lane]);  // 2-way alias
      float hv;
      if (LAYER_KIND == 0){
        int ty = __builtin_amdgcn_readlane(tv, i);
        hv = (ty & 2) ? ((ty & 1) ? e3 : e2) : ((ty & 1) ? e1 : e0);
      } else {
        hv = hS[i][lane];
      }
      float g = rw * hv;
      const uint4* yq = (const uint4*)&yS[i][0];   // uniform -> broadcast
      uint4 ya = yq[0], yb = yq[1];
      float lo, hi;
      unpack2(ya.x, lo, hi); acc[0]  += g*lo; acc[1]  += g*hi;
      unpack2(ya.y, lo, hi); acc[2]  += g*lo; acc[3]  += g*hi;
      unpack2(ya.z, lo, hi); acc[4]  += g*lo; acc[5]  += g*hi;
      unpack2(ya.w, lo, hi); acc[6]  += g*lo; acc[7]  += g*hi;
      unpack2(yb.x, lo, hi); acc[8]  += g*lo; acc[9]  += g*hi;
      unpack2(yb.y, lo, hi); acc[10] += g*lo; acc[11] += g*hi;
      unpack2(yb.z, lo, hi); acc[12] += g*lo; acc[13] += g*hi;
      unpack2(yb.w, lo, hi); acc[14] += g*lo; acc[15] += g*hi;
    }
    ev = ev_n; sv = sv_n; tvp = tv_n; rv = rv_n;
    cb += 16;
  } while (cb < end);
#pragma unroll
  for (int s = 0; s < 16; s++) acc[s] *= INV_AVG;

  int ty = __builtin_amdgcn_readfirstlane(types[n]);
  float sc;
  if (LAYER_KIND == 0){
    sc = sc0t[ty*64 + lane];                   // precomputed per-type table
  } else {
    const float* Ws = Wsc + (size_t)ty*4096;
    const float* hrow = h_old + (size_t)n*64;
    float sc0 = 0.f, sc1 = 0.f, sc2 = 0.f, sc3 = 0.f;
#pragma unroll
    for (int c = 0; c < 64; c += 4){
      sc0 += hrow[c+0] * Ws[(c+0)*64 + lane];
      sc1 += hrow[c+1] * Ws[(c+1)*64 + lane];
      sc2 += hrow[c+2] * Ws[(c+2)*64 + lane];
      sc3 += hrow[c+3] * Ws[(c+3)*64 + lane];
    }
    sc = (sc0 + sc1) + (sc2 + sc3);
  }

  float inv0 = acc[0];
  float inv1 = acc[1]*acc[1] + acc[2]*acc[2] + acc[3]*acc[3];
  float inv2 = acc[4]*acc[4] + acc[5]*acc[5] + acc[6]*acc[6] + acc[7]*acc[7]
             + acc[8]*acc[8];
  float inv3 = acc[9]*acc[9] + acc[10]*acc[10] + acc[11]*acc[11] + acc[12]*acc[12]
             + acc[13]*acc[13] + acc[14]*acc[14] + acc[15]*acc[15];
  const float* wp = wprod + ty*4;
  float hn = inv0*wp[0] + inv1*wp[1] + inv2*wp[2] + inv3*wp[3] + sc;
  if (LAYER_KIND == 0)
    h_new[(size_t)n*64 + lane] = hn;   // layer-1 output consumed in-kernel

  float ev_;
  if (LAYER_KIND == 0){
    float p = hn * wro0[lane];
#pragma unroll
    for (int off = 32; off >= 1; off >>= 1) p += __shfl_xor(p, off, 64);
    ev_ = p;
  } else {
    hn_l[lane] = hn;
    WSYNC();
    int j = lane & 15;
    float pj = 0.0f;
#pragma unroll
    for (int c = 0; c < 64; c++)
      pj += hn_l[c] * Wro1a[c*16 + j];
    float evj = silu_f(pj) * wro1b[j];
    evj += __shfl_xor(evj, 8, 64);
    evj += __shfl_xor(evj, 4, 64);
    evj += __shfl_xor(evj, 2, 64);
    evj += __shfl_xor(evj, 1, 64);
    ev_ = evj;
  }
  // contention-spread energy: consecutive nodes hit different copies
  if (lane == 0) atomicAdd(&ene2[(n & 7)*NGRP + batch[n]], ev_);
}

// ---------------- final output: reduce ene2 copies + format convert ----------
__global__ void k_out(const float* __restrict__ ene2, const void* __restrict__ pos,
                      void* __restrict__ out){
  int fl = detect_fl(pos);
  int t = threadIdx.x;
  if (t < NGRP){
    float v = 0.0f;
#pragma unroll
    for (int k = 0; k < 8; k++) v += ene2[k*NGRP + t];
    if (fl) ((bf16*)out)[t] = __float2bfloat16(v);
    else    ((float*)out)[t] = v;
  }
}

static inline size_t rup(size_t x){ return (x + 255) & ~(size_t)255; }

extern "C" void kernel_launch(void* const* d_in, const int* in_sizes, int n_in,
                              void* d_out, int out_size, void* d_ws, size_t ws_size,
                              hipStream_t stream) {
  const void* pos   = d_in[0];
  const int*  types = (const int*)d_in[1];
  const int*  ei    = (const int*)d_in[2];
  const int*  batch = (const int*)d_in[3];
  const void* Wemb  = d_in[4];
  const void* Wr1   = d_in[5];
  const void* Wr2   = d_in[6];
  const void* Wr3   = d_in[7];
  const void* Wsc   = d_in[8];
  const void* wprod = d_in[9];
  const void* wro0  = d_in[10];
  const void* Wro1a = d_in[11];
  const void* wro1b = d_in[12];

  char* w = (char*)d_ws;
  float* ene2     = (float*)w; w += 512;                      // 8 copies x 16
  int*   cursor   = (int*)  w; w += rup((size_t)N_NODES*4);   // contiguous w/ ene2
  float* cv       = (float*)w; w += rup((size_t)CVT_N*4);
  short* swz      = (short*)w; w += rup((size_t)SWZ_N*2);
  int*   sslot    = (int*)  w; w += rup((size_t)N_SLOTS*4) + 256;
  unsigned char* tsl = (unsigned char*)w; w += rup((size_t)N_SLOTS) + 256;
  int*   eslot    = (int*)  w; w += rup((size_t)N_SLOTS*4) + 256;
  float* hbuf     = (float*)w; w += rup((size_t)N_NODES*64*4);
  float* rbuf     = (float*)w; w += rup((size_t)N_SLOTS*4) + 256;
  unsigned short* Yb = (unsigned short*)w; w += rup((size_t)N_EDGES*16*2);
  w += 4096;   // slack

  // one memset zeroes ene2 (512B) + cursor (32KB) in one shot
  hipMemsetAsync(ene2, 0, 512 + (size_t)N_NODES*4, stream);

  k_setup<<<SETUP_GRID, 256, 0, stream>>>(pos, types, ei,
      Wemb, Wsc, wprod, wro0, Wro1a, wro1b, Wr1, Wr2, Wr3,
      cursor, sslot, tsl, eslot, Yb, rbuf, cv, swz);

  k_gu<0><<<N_NODES, 64, 0, stream>>>(swz, rbuf, tsl, sslot, eslot,
      hbuf /*unused*/, hbuf /*h_new*/, Yb, cursor, types,
      cv + CV_SC, cv + CV_PROD, cv + CV_EMB, cv + CV_SC0T,
      cv + CV_RO0, cv + CV_RO1A, cv + CV_RO1B, batch, ene2);
  k_gu<1><<<N_NODES, 64, 0, stream>>>(swz + SWZ_PER_L, rbuf, tsl, sslot, eslot,
      hbuf /*h_old*/, hbuf /*unused*/, Yb, cursor, types,
      cv + CV_SC + (size_t)NELM*4096, cv + CV_PROD + NELM*4, cv + CV_EMB,
      cv + CV_SC0T, cv + CV_RO0, cv + CV_RO1A, cv + CV_RO1B, batch, ene2);

  k_out<<<1, 64, 0, stream>>>(ene2, pos, d_out);
}

// Round 16
// 165.947 us; speedup vs baseline: 1.1146x; 1.0401x over previous
//
#include <hip/hip_runtime.h>
#include <hip/hip_bf16.h>
#include <math.h>

#define N_NODES 8192
#define N_EDGES 131072
#define NGRP 16
#define NLAY 2
#define NELM 4
#define SLOT_STRIDE 64     // fixed per-node slot region; P(deg>64) ~ 1e-15
#define N_SLOTS (N_NODES*SLOT_STRIDE)
constexpr float INV_AVG = 1.0f / 16.0f;
constexpr float PI_F = 3.14159265358979323846f;

// converted fp32 buffer layout (element offsets) -- only what k_gu/k_out need.
#define CV_EMB   0        // 256
#define CV_SC    256      // 32768 (natural [l][ty][c:64][d:64])
#define CV_PROD  33024    // 32
#define CV_RO0   33056    // 64
#define CV_RO1A  33120    // 1024
#define CV_RO1B  34144    // 16
#define CV_SC0T  34160    // 256 (layer-0 sc term per type: Wemb[ty] @ Wsc0[ty])
#define CVT_WORK 34160
#define CVT_N    34416

// swizzled bf16 MFMA B-fragment weight buffer: per layer 10240 shorts
#define SWZ_PER_L 10240
#define SWZ_N     20480

// k_setup fused-dispatch block ranges: [geom][cvt][swz][sc0tab]
#define B_GEOM 512
#define B_CVT  134
#define B_SWZ  80
#define SETUP_GRID (B_GEOM + B_CVT + B_SWZ + 1)

typedef __hip_bfloat16 bf16;
typedef __attribute__((ext_vector_type(8))) short bf16x8;
typedef __attribute__((ext_vector_type(4))) float f32x4;

__device__ __forceinline__ float silu_f(float x){ return x / (1.0f + __expf(-x)); }
__device__ __forceinline__ float bfbits2f(unsigned short u){
  return __uint_as_float(((unsigned)u) << 16);
}
__device__ __forceinline__ void unpack2(unsigned u, float& lo, float& hi){
  lo = __uint_as_float(u << 16);
  hi = __uint_as_float(u & 0xffff0000u);
}
__device__ __forceinline__ short f2bs(float v){
  union { bf16 b; short s; } u; u.b = __float2bfloat16(v); return u.s;
}
__device__ __forceinline__ float ldf(const void* p, int i, int flag){
  if (flag) return bfbits2f(((const unsigned short*)p)[i]);
  return ((const float*)p)[i];
}
// per-wave input dtype detection (reads first 128 ushorts of pos; L1/L2-hot).
__device__ __forceinline__ int detect_fl(const void* pos){
  int lane = threadIdx.x & 63;
  const unsigned short* u = (const unsigned short*)pos;
  float va = bfbits2f(u[2*lane]), vb = bfbits2f(u[2*lane+1]);
  bool bad = !(fabsf(va) <= 1000.0f) || !(fabsf(vb) <= 1000.0f);
  return (__ballot(bad) == 0ull) ? 1 : 0;
}
__device__ __forceinline__ void WSYNC(){ __builtin_amdgcn_wave_barrier(); }

// async global->LDS DMA: data never touches VGPRs.
__device__ __forceinline__ void gl_lds4(const void* g, void* l){
  __builtin_amdgcn_global_load_lds(
      (const __attribute__((address_space(1))) unsigned*)g,
      (__attribute__((address_space(3))) unsigned*)l, 4, 0, 0);
}

// ===== K1: fused {edge geom + fixed-stride CSR, cvt, weight-swz, sc0-table} ==
// Geom writes Y LINEARLY by edge (coalesced) and ONE 16B meta scatter per
// edge: meta[slot] = {src|(type<<16), edge, bits(r), 0}. (R15 had 4 separate
// scatters = 4 write-allocated lines/edge = ~33MB; now 1 line = ~8MB.)
__global__ void k_setup(const void* __restrict__ pos, const int* __restrict__ types,
                        const int* __restrict__ ei,
                        const void* __restrict__ Wemb, const void* __restrict__ Wsc,
                        const void* __restrict__ wprod, const void* __restrict__ wro0,
                        const void* __restrict__ Wro1a, const void* __restrict__ wro1b,
                        const void* __restrict__ Wr1, const void* __restrict__ Wr2,
                        const void* __restrict__ Wr3,
                        int* __restrict__ cursor, uint4* __restrict__ meta,
                        unsigned short* __restrict__ Yb,
                        float* __restrict__ cv, short* __restrict__ swz){
  int b = blockIdx.x, tix = threadIdx.x;
  int fl = detect_fl(pos);
  if (b < B_GEOM){                     // ---- edge geometry + slot assignment ----
    int e = b*256 + tix;
    int s = ei[e], d = ei[N_EDGES + e];
    int slot = (d << 6) + atomicAdd(&cursor[d], 1);
    float vx = ldf(pos, d*3+0, fl) - ldf(pos, s*3+0, fl);
    float vy = ldf(pos, d*3+1, fl) - ldf(pos, s*3+1, fl);
    float vz = ldf(pos, d*3+2, fl) - ldf(pos, s*3+2, fl);
    float r = sqrtf(vx*vx + vy*vy + vz*vz + 1e-12f);
    float ir = 1.0f / r;
    float x = vx*ir, y = vy*ir, z = vz*ir;
    const float s3 = 1.7320508075688772f, s15 = 3.872983346207417f, s5 = 2.23606797749979f;
    const float s105 = 10.246950765959598f, s7 = 2.6457513110645907f;
    const float c35 = 2.091650066335189f, c21 = 1.6201851746019651f;
    float x2 = x*x, y2 = y*y, z2 = z*z;
    float ys[16] = {
      1.0f, s3*x, s3*y, s3*z,
      s15*x*y, s15*y*z, 0.5f*s5*(3.0f*z2-1.0f), s15*x*z,
      0.5f*s15*(x2-y2), c35*y*(3.0f*x2-y2), s105*x*y*z, c21*y*(5.0f*z2-1.0f),
      0.5f*s7*(5.0f*z2*z-3.0f*z), c21*x*(5.0f*z2-1.0f), 0.5f*s105*z*(x2-y2),
      c35*x*(x2-3.0f*y2) };
    union { bf16 bb[16]; uint4 u[2]; } pk;
#pragma unroll
    for (int k = 0; k < 16; k++) pk.bb[k] = __float2bfloat16(ys[k]);
    uint4* yp = (uint4*)(Yb + (size_t)e*16);   // LINEAR by edge (coalesced)
    yp[0] = pk.u[0];
    yp[1] = pk.u[1];
    meta[slot] = make_uint4((unsigned)s | ((unsigned)types[s] << 16),
                            (unsigned)e, __float_as_uint(r), 0u);
    return;
  }
  if (b < B_GEOM + B_CVT){             // ---- fp32 conversion ----
    int i = (b - B_GEOM)*256 + tix;
    if (i < 256)  { cv[CV_EMB + i] = ldf(Wemb, i, fl); return; }
    if (i < 33024){ int j=i-256;   cv[CV_SC  + j] = ldf(Wsc,  j, fl); return; }
    if (i < 33056){ int j=i-33024; cv[CV_PROD+ j] = ldf(wprod,j, fl); return; }
    if (i < 33120){ int j=i-33056; cv[CV_RO0 + j] = ldf(wro0, j, fl); return; }
    if (i < 34144){ int j=i-33120; cv[CV_RO1A+ j] = ldf(Wro1a,j, fl); return; }
    if (i < CVT_WORK){ int j=i-34144; cv[CV_RO1B+ j] = ldf(wro1b,j, fl); return; }
    return;
  }
  if (b < B_GEOM + B_CVT + B_SWZ){     // ---- MFMA B-fragment bf16 weights ----
    int i = (b - B_GEOM - B_CVT)*256 + tix;   // 20480 exact
    int l = i / SWZ_PER_L, w = i % SWZ_PER_L;
    float v;
    if (w < 2048){
      int t = w >> 9, q = (w >> 7) & 3, n = (w >> 3) & 15, j = w & 7;
      int k = q*8 + j;
      v = (k < 8) ? ldf(Wr1, l*512 + k*64 + t*16 + n, fl) : 0.0f;
    } else if (w < 6144){
      int w2 = w - 2048;
      int nt = w2 >> 10, kt = (w2 >> 9) & 1, q = (w2 >> 7) & 3, n = (w2 >> 3) & 15, j = w2 & 7;
      int k = kt*32 + q*8 + j;
      v = ldf(Wr2, l*4096 + k*64 + nt*16 + n, fl);
    } else {
      int w3 = w - 6144;
      int nt = w3 >> 10, kt = (w3 >> 9) & 1, q = (w3 >> 7) & 3, n = (w3 >> 3) & 15, j = w3 & 7;
      int k = kt*32 + q*8 + j;
      v = ldf(Wr3, l*4096 + k*64 + nt*16 + n, fl);
    }
    swz[i] = f2bs(v);
    return;
  }
  // ---- layer-0 sc table: sc0t[ty][d] = sum_c Wemb[ty][c] * Wsc0[ty][c][d] ----
  {
    int ty = tix >> 6, d = tix & 63;
    float s = 0.0f;
#pragma unroll 8
    for (int c = 0; c < 64; c++)
      s += ldf(Wemb, ty*64 + c, fl) * ldf(Wsc, ty*4096 + c*64 + d, fl);
    cv[CV_SC0T + tix] = s;
  }
}

// ====== fused node kernel, ONE WAVE PER BLOCK (node = blockIdx.x) ======
// R15-verified body; metadata now ONE uint4 load per chunk (was 4 separate
// sslot/tsl/eslot/rbuf loads) -- shorter scalar chain, coalesced 256B read.
#define ROWS 72
template<int LAYER_KIND>
__global__ void __launch_bounds__(64) k_gu(const short* __restrict__ sw,
        const uint4* __restrict__ meta,
        const float* __restrict__ h_old,
        float* __restrict__ h_new, const unsigned short* __restrict__ Yb,
        const int* __restrict__ cursor, const int* __restrict__ types,
        const float* __restrict__ Wsc, const float* __restrict__ wprod,
        const float* __restrict__ wemb, const float* __restrict__ sc0t,
        const float* __restrict__ wro0,
        const float* __restrict__ Wro1a, const float* __restrict__ wro1b,
        const int* __restrict__ batch, float* __restrict__ ene2){
  __shared__ __align__(16) short A_[16*ROWS];                    // 2.25 KB
  __shared__ __align__(16) float hS[LAYER_KIND ? 16 : 1][64];    // 4 KB (L1)
  __shared__ __align__(16) unsigned short yS[16][16];            // 0.5 KB
  __shared__ float hn_l[64];
  int lane = threadIdx.x;
  int q = lane >> 4, nn = lane & 15;
  int n = blockIdx.x;
  int beg = n << 6;
  short* A = A_;

  const bf16x8* S1 = (const bf16x8*)(sw);
  const bf16x8* S2 = (const bf16x8*)(sw + 2048);
  const bf16x8* S3 = (const bf16x8*)(sw + 6144);

  // layer-0 embedding rows (4 types x 64 ch) in registers
  float e0=0.f, e1=0.f, e2=0.f, e3=0.f;
  if (LAYER_KIND == 0){
    e0 = wemb[lane]; e1 = wemb[64+lane]; e2 = wemb[128+lane]; e3 = wemb[192+lane];
  }

  // ---- prefetch chunk-0 metadata (ONE vector load) || cursor load ----
  int dcnt = cursor[n];
  uint4 mC = meta[beg + nn];
  int end = beg + dcnt;

  float acc[16];
#pragma unroll
  for (int s = 0; s < 16; s++) acc[s] = 0.0f;

  int cb = beg;
  do {
    int cnt = min(16, end - cb);     // known from registers; no memory dep
    WSYNC();   // fence: prior chunk's LDS reads precede this chunk's DMA/MLP
    // ---------- phase A: issue DMAs ----------
    int ev = (int)mC.y;
    // Y rows via edge indirection: 2 DMAs x 8 rows x 32B; per-lane global src
    {
      int er0 = __shfl(ev, (lane >> 3)) & (N_EDGES - 1);
      gl_lds4((const char*)Yb + (size_t)er0*32 + (lane & 7)*4, &yS[0][0]);
      int er1 = __shfl(ev, 8 + (lane >> 3)) & (N_EDGES - 1);
      gl_lds4((const char*)Yb + (size_t)er1*32 + (lane & 7)*4, &yS[8][0]);
    }
    int tv = (int)((mC.x >> 16) & 3u);
    if (LAYER_KIND == 1){
      int sv = (int)(mC.x & 0xFFFFu);
      for (int i = 0; i < cnt; i++){   // bounded: no wasted tail DMAs
        int src = __builtin_amdgcn_readlane(sv, i) & (N_NODES - 1);
        gl_lds4(h_old + (size_t)src*64 + lane, &hS[i][0]);
      }
    }
    float rv = __uint_as_float(mC.z);
    // prefetch next chunk's metadata (issued early, consumed next iteration)
    uint4 mN = meta[min(cb + 16 + nn, N_SLOTS - 1)];
    // ---------- phase B: wave-private MFMA radial MLP (hides DMA) ----------
    {
      float r = rv;
      float xc = r * 0.2f;
      float f = 0.0f;
      if (xc < 1.0f){
        float x3 = xc*xc*xc, x6 = x3*x3, x7 = x6*xc, x8 = x7*xc;
        f = 1.0f - 28.0f*x6 + 48.0f*x7 - 21.0f*x8;
      }
      float bs = 0.6324555320336759f * f / r;
      float t0 = PI_F * r * 0.2f;
      bf16x8 af1 = {0,0,0,0,0,0,0,0};
      if (q == 0){
#pragma unroll
        for (int j = 0; j < 8; j++) af1[j] = f2bs(bs * __sinf((float)(j+1) * t0));
      }
      f32x4 macc[4];
#pragma unroll
      for (int t = 0; t < 4; t++){
        bf16x8 b = S1[t*64 + q*16 + nn];
        f32x4 z = {0.f,0.f,0.f,0.f};
        macc[t] = __builtin_amdgcn_mfma_f32_16x16x32_bf16(af1, b, z, 0, 0, 0);
      }
#pragma unroll
      for (int t = 0; t < 4; t++)
#pragma unroll
        for (int rg = 0; rg < 4; rg++)
          A[(q*4+rg)*ROWS + t*16 + nn] = f2bs(silu_f(macc[t][rg]));
      WSYNC();
      bf16x8 a0 = *(const bf16x8*)&A[nn*ROWS + 0*32 + q*8];
      bf16x8 a1 = *(const bf16x8*)&A[nn*ROWS + 1*32 + q*8];
      WSYNC();
#pragma unroll
      for (int t = 0; t < 4; t++){
        f32x4 z = {0.f,0.f,0.f,0.f};
        bf16x8 b0 = S2[t*128 + 0*64 + q*16 + nn];
        bf16x8 b1 = S2[t*128 + 1*64 + q*16 + nn];
        z = __builtin_amdgcn_mfma_f32_16x16x32_bf16(a0, b0, z, 0, 0, 0);
        z = __builtin_amdgcn_mfma_f32_16x16x32_bf16(a1, b1, z, 0, 0, 0);
        macc[t] = z;
      }
#pragma unroll
      for (int t = 0; t < 4; t++)
#pragma unroll
        for (int rg = 0; rg < 4; rg++)
          A[(q*4+rg)*ROWS + t*16 + nn] = f2bs(silu_f(macc[t][rg]));
      WSYNC();
      a0 = *(const bf16x8*)&A[nn*ROWS + 0*32 + q*8];
      a1 = *(const bf16x8*)&A[nn*ROWS + 1*32 + q*8];
      WSYNC();
#pragma unroll
      for (int t = 0; t < 4; t++){
        f32x4 z = {0.f,0.f,0.f,0.f};
        bf16x8 b0 = S3[t*128 + 0*64 + q*16 + nn];
        bf16x8 b1 = S3[t*128 + 1*64 + q*16 + nn];
        z = __builtin_amdgcn_mfma_f32_16x16x32_bf16(a0, b0, z, 0, 0, 0);
        z = __builtin_amdgcn_mfma_f32_16x16x32_bf16(a1, b1, z, 0, 0, 0);
        macc[t] = z;
      }
      // final Rw stays in A: layout A[slot*ROWS + ch]
#pragma unroll
      for (int t = 0; t < 4; t++)
#pragma unroll
        for (int rg = 0; rg < 4; rg++)
          A[(q*4+rg)*ROWS + t*16 + nn] = f2bs(macc[t][rg]);
      WSYNC();
    }
    // ---------- phase C: wait DMAs, accumulate (all wave-private) ----------
    asm volatile("s_waitcnt vmcnt(0)" ::: "memory");
    __builtin_amdgcn_sched_barrier(0);
    for (int i = 0; i < cnt; i++){
      float rw = bfbits2f((unsigned short)A[i*ROWS + lane]);  // 2-way alias
      float hv;
      if (LAYER_KIND == 0){
        int ty = __builtin_amdgcn_readlane(tv, i);
        hv = (ty & 2) ? ((ty & 1) ? e3 : e2) : ((ty & 1) ? e1 : e0);
      } else {
        hv = hS[i][lane];
      }
      float g = rw * hv;
      const uint4* yq = (const uint4*)&yS[i][0];   // uniform -> broadcast
      uint4 ya = yq[0], yb = yq[1];
      float lo, hi;
      unpack2(ya.x, lo, hi); acc[0]  += g*lo; acc[1]  += g*hi;
      unpack2(ya.y, lo, hi); acc[2]  += g*lo; acc[3]  += g*hi;
      unpack2(ya.z, lo, hi); acc[4]  += g*lo; acc[5]  += g*hi;
      unpack2(ya.w, lo, hi); acc[6]  += g*lo; acc[7]  += g*hi;
      unpack2(yb.x, lo, hi); acc[8]  += g*lo; acc[9]  += g*hi;
      unpack2(yb.y, lo, hi); acc[10] += g*lo; acc[11] += g*hi;
      unpack2(yb.z, lo, hi); acc[12] += g*lo; acc[13] += g*hi;
      unpack2(yb.w, lo, hi); acc[14] += g*lo; acc[15] += g*hi;
    }
    mC = mN;
    cb += 16;
  } while (cb < end);
#pragma unroll
  for (int s = 0; s < 16; s++) acc[s] *= INV_AVG;

  int ty = __builtin_amdgcn_readfirstlane(types[n]);
  float sc;
  if (LAYER_KIND == 0){
    sc = sc0t[ty*64 + lane];                   // precomputed per-type table
  } else {
    const float* Ws = Wsc + (size_t)ty*4096;
    const float* hrow = h_old + (size_t)n*64;
    float sc0 = 0.f, sc1 = 0.f, sc2 = 0.f, sc3 = 0.f;
#pragma unroll
    for (int c = 0; c < 64; c += 4){
      sc0 += hrow[c+0] * Ws[(c+0)*64 + lane];
      sc1 += hrow[c+1] * Ws[(c+1)*64 + lane];
      sc2 += hrow[c+2] * Ws[(c+2)*64 + lane];
      sc3 += hrow[c+3] * Ws[(c+3)*64 + lane];
    }
    sc = (sc0 + sc1) + (sc2 + sc3);
  }

  float inv0 = acc[0];
  float inv1 = acc[1]*acc[1] + acc[2]*acc[2] + acc[3]*acc[3];
  float inv2 = acc[4]*acc[4] + acc[5]*acc[5] + acc[6]*acc[6] + acc[7]*acc[7]
             + acc[8]*acc[8];
  float inv3 = acc[9]*acc[9] + acc[10]*acc[10] + acc[11]*acc[11] + acc[12]*acc[12]
             + acc[13]*acc[13] + acc[14]*acc[14] + acc[15]*acc[15];
  const float* wp = wprod + ty*4;
  float hn = inv0*wp[0] + inv1*wp[1] + inv2*wp[2] + inv3*wp[3] + sc;
  if (LAYER_KIND == 0)
    h_new[(size_t)n*64 + lane] = hn;   // layer-1 output consumed in-kernel

  float ev_;
  if (LAYER_KIND == 0){
    float p = hn * wro0[lane];
#pragma unroll
    for (int off = 32; off >= 1; off >>= 1) p += __shfl_xor(p, off, 64);
    ev_ = p;
  } else {
    hn_l[lane] = hn;
    WSYNC();
    int j = lane & 15;
    float pj = 0.0f;
#pragma unroll
    for (int c = 0; c < 64; c++)
      pj += hn_l[c] * Wro1a[c*16 + j];
    float evj = silu_f(pj) * wro1b[j];
    evj += __shfl_xor(evj, 8, 64);
    evj += __shfl_xor(evj, 4, 64);
    evj += __shfl_xor(evj, 2, 64);
    evj += __shfl_xor(evj, 1, 64);
    ev_ = evj;
  }
  // contention-spread energy: consecutive nodes hit different copies
  if (lane == 0) atomicAdd(&ene2[(n & 7)*NGRP + batch[n]], ev_);
}

// ---------------- final output: reduce ene2 copies + format convert ----------
__global__ void k_out(const float* __restrict__ ene2, const void* __restrict__ pos,
                      void* __restrict__ out){
  int fl = detect_fl(pos);
  int t = threadIdx.x;
  if (t < NGRP){
    float v = 0.0f;
#pragma unroll
    for (int k = 0; k < 8; k++) v += ene2[k*NGRP + t];
    if (fl) ((bf16*)out)[t] = __float2bfloat16(v);
    else    ((float*)out)[t] = v;
  }
}

static inline size_t rup(size_t x){ return (x + 255) & ~(size_t)255; }

extern "C" void kernel_launch(void* const* d_in, const int* in_sizes, int n_in,
                              void* d_out, int out_size, void* d_ws, size_t ws_size,
                              hipStream_t stream) {
  const void* pos   = d_in[0];
  const int*  types = (const int*)d_in[1];
  const int*  ei    = (const int*)d_in[2];
  const int*  batch = (const int*)d_in[3];
  const void* Wemb  = d_in[4];
  const void* Wr1   = d_in[5];
  const void* Wr2   = d_in[6];
  const void* Wr3   = d_in[7];
  const void* Wsc   = d_in[8];
  const void* wprod = d_in[9];
  const void* wro0  = d_in[10];
  const void* Wro1a = d_in[11];
  const void* wro1b = d_in[12];

  char* w = (char*)d_ws;
  float* ene2     = (float*)w; w += 512;                      // 8 copies x 16
  int*   cursor   = (int*)  w; w += rup((size_t)N_NODES*4);   // contiguous w/ ene2
  float* cv       = (float*)w; w += rup((size_t)CVT_N*4);
  short* swz      = (short*)w; w += rup((size_t)SWZ_N*2);
  uint4* meta     = (uint4*)w; w += rup((size_t)N_SLOTS*16) + 256;
  float* hbuf     = (float*)w; w += rup((size_t)N_NODES*64*4);
  unsigned short* Yb = (unsigned short*)w; w += rup((size_t)N_EDGES*16*2);
  w += 4096;   // slack

  // one memset zeroes ene2 (512B) + cursor (32KB) in one shot
  hipMemsetAsync(ene2, 0, 512 + (size_t)N_NODES*4, stream);

  k_setup<<<SETUP_GRID, 256, 0, stream>>>(pos, types, ei,
      Wemb, Wsc, wprod, wro0, Wro1a, wro1b, Wr1, Wr2, Wr3,
      cursor, meta, Yb, cv, swz);

  k_gu<0><<<N_NODES, 64, 0, stream>>>(swz, meta,
      hbuf /*unused*/, hbuf /*h_new*/, Yb, cursor, types,
      cv + CV_SC, cv + CV_PROD, cv + CV_EMB, cv + CV_SC0T,
      cv + CV_RO0, cv + CV_RO1A, cv + CV_RO1B, batch, ene2);
  k_gu<1><<<N_NODES, 64, 0, stream>>>(swz + SWZ_PER_L, meta,
      hbuf /*h_old*/, hbuf /*unused*/, Yb, cursor, types,
      cv + CV_SC + (size_t)NELM*4096, cv + CV_PROD + NELM*4, cv + CV_EMB,
      cv + CV_SC0T, cv + CV_RO0, cv + CV_RO1A, cv + CV_RO1B, batch, ene2);

  k_out<<<1, 64, 0, stream>>>(ene2, pos, d_out);
}